// Round 7
// baseline (861.470 us; speedup 1.0000x reference)
//
#include <hip/hip_runtime.h>
#include <hip/hip_bf16.h>

#define D_FEAT 128
#define D4 (D_FEAT / 4)
#define BKT_SHIFT 7            // 128 nodes per bucket
#define BKT_NODES 128
#define NSLOT 8                // one slot per XCD (blockIdx % 8 round-robin)
#define CUR_PAD 16             // one cursor per 64B line

// ---------- main path: XCD-slotted bucket partition + LDS-tile accumulate ----

// Fused: threads [0,E) histogram (bucket,slot); threads [E, E+n4) convert
// fp32 features -> bf16 table. slot=(e>>8)&7 is a pure function of e, so the
// counts here exactly match the partition kernel's cursor claims.
__global__ void hist_cvt_kernel(const int* __restrict__ dst,
                                int* __restrict__ cur, int E,
                                const float4* __restrict__ fin,
                                __hip_bfloat162* __restrict__ fout, int n4) {
    int t = blockIdx.x * blockDim.x + threadIdx.x;
    if (t < E) {
        int d = dst[t];
        int slot = (t >> 8) & (NSLOT - 1);
        atomicAdd(&cur[(((d >> BKT_SHIFT) << 3) + slot) * CUR_PAD], 1);
    } else {
        int i = t - E;
        if (i < n4) {
            float4 f = fin[i];
            fout[2 * i + 0] = __float22bfloat162_rn(make_float2(f.x, f.y));
            fout[2 * i + 1] = __float22bfloat162_rn(make_float2(f.z, f.w));
        }
    }
}

// Single block: exclusive scan over n = NBKT*8 (few thousand) strided counts.
// Writes base into offsets[] and back into the padded cursors (partition bumps).
__global__ void scan_small_kernel(int* __restrict__ cur,
                                  int* __restrict__ offsets, int n) {
    __shared__ int sdata[1024];
    int tid = threadIdx.x;
    int per = (n + 1023) >> 10;
    int base = tid * per;
    int sum = 0;
    for (int i = 0; i < per; i++) {
        int j = base + i;
        if (j < n) sum += cur[j * CUR_PAD];
    }
    sdata[tid] = sum;
    __syncthreads();
    for (int off = 1; off < 1024; off <<= 1) {
        int t = (tid >= off) ? sdata[tid - off] : 0;
        __syncthreads();
        sdata[tid] += t;
        __syncthreads();
    }
    int excl = sdata[tid] - sum;
    for (int i = 0; i < per; i++) {
        int j = base + i;
        if (j < n) {
            int c = cur[j * CUR_PAD];
            offsets[j] = excl;
            cur[j * CUR_PAD] = excl;
            excl += c;
        }
    }
}

// Partition edges into (bucket,slot) regions. All writes to a slot-s region
// come from blocks with blockIdx%8==s (one XCD) -> lines fill in that XCD's
// L2 before writeback (kills the 8x partial-line write amplification).
__global__ void partition_kernel(const int* __restrict__ src,
                                 const int* __restrict__ dst,
                                 const float* __restrict__ vals,
                                 int* __restrict__ cur,
                                 int2* __restrict__ spack, int E) {
    int e = blockIdx.x * blockDim.x + threadIdx.x;
    if (e >= E) return;
    int d = dst[e];
    int s = src[e];
    float v = vals[e];
    int slot = (e >> 8) & (NSLOT - 1);
    int idx = ((d >> BKT_SHIFT) << 3) + slot;
    int pos = atomicAdd(&cur[idx * CUR_PAD], 1);
    spack[pos] = make_int2(s | ((d & (BKT_NODES - 1)) << 16), __float_as_int(v));
}

// One block per bucket: 128x128 fp32 tile in LDS, stream slot regions,
// LDS-atomic accumulate v * feat_bf16[src], write out = tile + bias coalesced.
__global__ __launch_bounds__(256) void bucket_accum_kernel(
        const int* __restrict__ offsets,      // region starts [NBKT*8]
        const int* __restrict__ cur,          // region ends (padded) [NBKT*8*16]
        const int2* __restrict__ spack,
        const __hip_bfloat162* __restrict__ feat,
        const float* __restrict__ bias,
        float* __restrict__ out, int N) {
    __shared__ float acc[BKT_NODES * D_FEAT];   // 64 KiB
    int b = blockIdx.x;
    int tid = threadIdx.x;
    int wave = tid >> 6;
    int lane = tid & 63;

    float4* a4 = (float4*)acc;
    for (int i = tid; i < BKT_NODES * D_FEAT / 4; i += 256)
        a4[i] = make_float4(0.f, 0.f, 0.f, 0.f);
    __syncthreads();

    for (int sidx = 0; sidx < NSLOT; sidx++) {
        int idx = (b << 3) + sidx;
        int start = offsets[idx];
        int cnt = cur[idx * CUR_PAD] - start;
        const int2* reg = spack + start;
        int lo = (cnt * wave) >> 2;
        int hi = (cnt * (wave + 1)) >> 2;
        int i = lo;
        for (; i + 4 <= hi; i += 4) {
            int2 r0 = reg[i + 0];
            int2 r1 = reg[i + 1];
            int2 r2 = reg[i + 2];
            int2 r3 = reg[i + 3];
            float2 f0 = __bfloat1622float2(feat[(size_t)(r0.x & 0xFFFF) * 64 + lane]);
            float2 f1 = __bfloat1622float2(feat[(size_t)(r1.x & 0xFFFF) * 64 + lane]);
            float2 f2 = __bfloat1622float2(feat[(size_t)(r2.x & 0xFFFF) * 64 + lane]);
            float2 f3 = __bfloat1622float2(feat[(size_t)(r3.x & 0xFFFF) * 64 + lane]);
            float v0 = __int_as_float(r0.y);
            float v1 = __int_as_float(r1.y);
            float v2 = __int_as_float(r2.y);
            float v3 = __int_as_float(r3.y);
            int row0 = (r0.x >> 16) & (BKT_NODES - 1);
            int row1 = (r1.x >> 16) & (BKT_NODES - 1);
            int row2 = (r2.x >> 16) & (BKT_NODES - 1);
            int row3 = (r3.x >> 16) & (BKT_NODES - 1);
            atomicAdd(&acc[row0 * D_FEAT + lane * 2 + 0], v0 * f0.x);
            atomicAdd(&acc[row0 * D_FEAT + lane * 2 + 1], v0 * f0.y);
            atomicAdd(&acc[row1 * D_FEAT + lane * 2 + 0], v1 * f1.x);
            atomicAdd(&acc[row1 * D_FEAT + lane * 2 + 1], v1 * f1.y);
            atomicAdd(&acc[row2 * D_FEAT + lane * 2 + 0], v2 * f2.x);
            atomicAdd(&acc[row2 * D_FEAT + lane * 2 + 1], v2 * f2.y);
            atomicAdd(&acc[row3 * D_FEAT + lane * 2 + 0], v3 * f3.x);
            atomicAdd(&acc[row3 * D_FEAT + lane * 2 + 1], v3 * f3.y);
        }
        for (; i < hi; i++) {
            int2 r = reg[i];
            float2 f = __bfloat1622float2(feat[(size_t)(r.x & 0xFFFF) * 64 + lane]);
            float v = __int_as_float(r.y);
            int row = (r.x >> 16) & (BKT_NODES - 1);
            atomicAdd(&acc[row * D_FEAT + lane * 2 + 0], v * f.x);
            atomicAdd(&acc[row * D_FEAT + lane * 2 + 1], v * f.y);
        }
    }
    __syncthreads();

    int base_node = b << BKT_SHIFT;
    for (int i = tid; i < BKT_NODES * (D_FEAT / 4); i += 256) {
        int row = i >> 5;          // 32 float4 per row
        int col4 = i & 31;
        int node = base_node + row;
        if (node < N) {
            float4 s = ((float4*)acc)[i];
            float4 bb = ((const float4*)bias)[col4];
            s.x += bb.x; s.y += bb.y; s.z += bb.z; s.w += bb.w;
            ((float4*)out)[(size_t)node * (D_FEAT / 4) + col4] = s;
        }
    }
}

// ---------- fallback atomic path ----------

__global__ void init_bias_kernel(float4* __restrict__ out,
                                 const float4* __restrict__ bias, int n4) {
    int i = blockIdx.x * blockDim.x + threadIdx.x;
    if (i < n4) out[i] = bias[i & (D4 - 1)];
}

__global__ void spmm_edge_kernel(const int* __restrict__ src,
                                 const int* __restrict__ dst,
                                 const float* __restrict__ vals,
                                 const float4* __restrict__ feat,
                                 float* __restrict__ out, int n_edges) {
    int tid = blockIdx.x * blockDim.x + threadIdx.x;
    int e = tid >> 5;
    int lane = tid & 31;
    if (e >= n_edges) return;
    int s = src[e];
    int d = dst[e];
    float v = vals[e];
    float4 f = feat[(size_t)s * D4 + lane];
    float* o = out + (size_t)d * D_FEAT + lane * 4;
    atomicAdd(o + 0, v * f.x);
    atomicAdd(o + 1, v * f.y);
    atomicAdd(o + 2, v * f.z);
    atomicAdd(o + 3, v * f.w);
}

extern "C" void kernel_launch(void* const* d_in, const int* in_sizes, int n_in,
                              void* d_out, int out_size, void* d_ws, size_t ws_size,
                              hipStream_t stream) {
    const int* edge_index = (const int*)d_in[0];    // (2, E) int32
    const float* edge_vals = (const float*)d_in[1]; // (E,)
    const float* features  = (const float*)d_in[2]; // (N, 128)
    const float* bias      = (const float*)d_in[3]; // (128,)

    int E = in_sizes[1];
    int N = in_sizes[2] / D_FEAT;
    const int* src = edge_index;
    const int* dst = edge_index + E;
    float* out = (float*)d_out;

    int NBKT = (N + BKT_NODES - 1) >> BKT_SHIFT;
    int nseg = NBKT * NSLOT;                 // (bucket,slot) regions
    int n4 = N * D_FEAT / 4;

    // ws layout: fb16[N*128] bf16 | spack[E] int2 | cur[nseg*CUR_PAD] | offsets[nseg]
    size_t fb_bytes  = (size_t)N * D_FEAT * 2;
    size_t sp_bytes  = (size_t)E * 8;
    size_t cur_bytes = (size_t)nseg * CUR_PAD * 4;
    size_t off_bytes = (size_t)nseg * 4;
    size_t needed = fb_bytes + sp_bytes + cur_bytes + off_bytes;

    bool ok = (ws_size >= needed) && (N <= 65536) && (in_sizes[3] == D_FEAT) &&
              (nseg <= 8192);

    if (ok) {
        char* wp = (char*)d_ws;
        __hip_bfloat162* fb16 = (__hip_bfloat162*)wp;  wp += fb_bytes;
        int2* spack  = (int2*)wp;                      wp += sp_bytes;
        int* cur     = (int*)wp;                       wp += cur_bytes;
        int* offsets = (int*)wp;

        hipMemsetAsync(cur, 0, cur_bytes, stream);
        {
            int total = E + n4;
            int block = 256, grid = (total + block - 1) / block;
            hist_cvt_kernel<<<grid, block, 0, stream>>>(dst, cur, E,
                                                        (const float4*)features,
                                                        fb16, n4);
        }
        scan_small_kernel<<<1, 1024, 0, stream>>>(cur, offsets, nseg);
        {
            int block = 256, grid = (E + block - 1) / block;
            partition_kernel<<<grid, block, 0, stream>>>(src, dst, edge_vals,
                                                         cur, spack, E);
        }
        bucket_accum_kernel<<<NBKT, 256, 0, stream>>>(offsets, cur, spack, fb16,
                                                      bias, out, N);
    } else {
        int no4 = out_size / 4;
        {
            int block = 256, grid = (no4 + block - 1) / block;
            init_bias_kernel<<<grid, block, 0, stream>>>((float4*)out,
                                                         (const float4*)bias, no4);
        }
        {
            int block = 256;
            long long total = (long long)E * 32;
            int grid = (int)((total + block - 1) / block);
            spmm_edge_kernel<<<grid, block, 0, stream>>>(src, dst, edge_vals,
                                                         (const float4*)features,
                                                         out, E);
        }
    }
}

// Round 8
// 214.838 us; speedup vs baseline: 4.0099x; 4.0099x over previous
//
#include <hip/hip_runtime.h>
#include <hip/hip_bf16.h>

#define D_FEAT 128
#define D4 (D_FEAT / 4)
#define BKT_SHIFT 7            // 128 nodes per bucket
#define BKT_NODES 128
#define NSLOT 8                // one slot per XCD (blockIdx % 8 round-robin)
#define CUR_PAD 16             // one bucket-cursor per 64B line
#define SCAN_BLOCK 1024

// ---------- shared preprocessing ----------

// bkt_mode=1: idx=(bucket*8+slot)*CUR_PAD (NEW). bkt_mode=0: idx=d (MID).
// Threads [E, E+n4) convert fp32 features -> bf16 table.
__global__ void hist_cvt_kernel(const int* __restrict__ dst,
                                int* __restrict__ cur, int E,
                                const float4* __restrict__ fin,
                                __hip_bfloat162* __restrict__ fout, int n4,
                                int bkt_mode) {
    int t = blockIdx.x * blockDim.x + threadIdx.x;
    if (t < E) {
        int d = dst[t];
        int idx;
        if (bkt_mode) {
            int slot = (t >> 8) & (NSLOT - 1);
            idx = (((d >> BKT_SHIFT) << 3) + slot) * CUR_PAD;
        } else {
            idx = d;
        }
        atomicAdd(&cur[idx], 1);
    } else {
        int i = t - E;
        if (i < n4) {
            float4 f = fin[i];
            fout[2 * i + 0] = __float22bfloat162_rn(make_float2(f.x, f.y));
            fout[2 * i + 1] = __float22bfloat162_rn(make_float2(f.z, f.w));
        }
    }
}

// bkt_mode=1: pack x = src | localrow<<16 ; bkt_mode=0: x = src.
__global__ void partition_kernel(const int* __restrict__ src,
                                 const int* __restrict__ dst,
                                 const float* __restrict__ vals,
                                 int* __restrict__ cur,
                                 int2* __restrict__ spack, int E, int bkt_mode) {
    int e = blockIdx.x * blockDim.x + threadIdx.x;
    if (e >= E) return;
    int d = dst[e];
    int s = src[e];
    float v = vals[e];
    int idx, x;
    if (bkt_mode) {
        int slot = (e >> 8) & (NSLOT - 1);
        idx = (((d >> BKT_SHIFT) << 3) + slot) * CUR_PAD;
        x = (s & 0xFFFF) | ((d & (BKT_NODES - 1)) << 16);
    } else {
        idx = d;
        x = s;
    }
    int pos = atomicAdd(&cur[idx], 1);
    spack[pos] = make_int2(x, __float_as_int(v));
}

// ---------- NEW path: small scan + out-of-place per-bucket counting sort ----

// Single block: exclusive scan over n (few thousand) CUR_PAD-strided counts.
// Writes offsets[0..n] (offsets[n]=total) and resets cur to the base.
__global__ void scan_small_kernel(int* __restrict__ cur,
                                  int* __restrict__ offsets, int n) {
    __shared__ int sdata[1024];
    int tid = threadIdx.x;
    int per = (n + 1023) >> 10;
    int base = tid * per;
    int sum = 0;
    for (int i = 0; i < per; i++) {
        int j = base + i;
        if (j < n) sum += cur[j * CUR_PAD];
    }
    sdata[tid] = sum;
    __syncthreads();
    for (int off = 1; off < 1024; off <<= 1) {
        int t = (tid >= off) ? sdata[tid - off] : 0;
        __syncthreads();
        sdata[tid] += t;
        __syncthreads();
    }
    int excl = sdata[tid] - sum;
    for (int i = 0; i < per; i++) {
        int j = base + i;
        if (j < n) {
            int c = cur[j * CUR_PAD];
            offsets[j] = excl;
            cur[j * CUR_PAD] = excl;
            excl += c;
        }
    }
    if (tid == 1023) offsets[n] = sdata[1023];
}

// One block per bucket: counting-sort its contiguous edge range by local row.
// Reads spackA twice (coalesced), writes sorted spackB (block-local window),
// emits global per-node offsets. ~1.5 KB LDS -> full occupancy.
__global__ __launch_bounds__(256) void bucket_sort_kernel(
        const int* __restrict__ offsets,   // [nseg+1], bucket b spans [b*8,(b+1)*8)
        const int2* __restrict__ spackA,
        int2* __restrict__ spackB,
        int* __restrict__ nodeoff, int N, int NBKT) {
    __shared__ int hist[BKT_NODES];
    __shared__ int scanbuf[BKT_NODES];
    __shared__ int lcur[BKT_NODES];
    int b = blockIdx.x;
    int tid = threadIdx.x;
    int base = offsets[b << 3];
    int end  = offsets[(b + 1) << 3];
    int cnt = end - base;

    if (tid < BKT_NODES) hist[tid] = 0;
    __syncthreads();
    for (int i = tid; i < cnt; i += 256) {
        int row = (spackA[base + i].x >> 16) & (BKT_NODES - 1);
        atomicAdd(&hist[row], 1);
    }
    __syncthreads();
    if (tid < BKT_NODES) scanbuf[tid] = hist[tid];
    __syncthreads();
    for (int off = 1; off < BKT_NODES; off <<= 1) {
        int t = (tid < BKT_NODES && tid >= off) ? scanbuf[tid - off] : 0;
        __syncthreads();
        if (tid < BKT_NODES) scanbuf[tid] += t;
        __syncthreads();
    }
    if (tid < BKT_NODES) {
        int excl = scanbuf[tid] - hist[tid];
        lcur[tid] = excl;
        int node = (b << BKT_SHIFT) + tid;
        if (node <= N) nodeoff[node] = base + excl;
    }
    __syncthreads();
    for (int i = tid; i < cnt; i += 256) {
        int2 r = spackA[base + i];
        int row = (r.x >> 16) & (BKT_NODES - 1);
        int p = atomicAdd(&lcur[row], 1);
        spackB[base + p] = r;
    }
    if (b == NBKT - 1 && tid == 0) nodeoff[N] = end;
}

// ---------- MID path: hierarchical scan over N per-node counts (pad=1) -----

__global__ void block_sums_kernel(const int* __restrict__ counts,
                                  int* __restrict__ blocksums, int n) {
    __shared__ int sdata[SCAN_BLOCK];
    int tid = threadIdx.x;
    int i = blockIdx.x * SCAN_BLOCK + tid;
    sdata[tid] = (i < n) ? counts[i] : 0;
    __syncthreads();
    for (int off = SCAN_BLOCK / 2; off > 0; off >>= 1) {
        if (tid < off) sdata[tid] += sdata[tid + off];
        __syncthreads();
    }
    if (tid == 0) blocksums[blockIdx.x] = sdata[0];
}

__global__ void scan_sums_kernel(int* __restrict__ blocksums, int nb) {
    __shared__ int sdata[256];
    int tid = threadIdx.x;
    int v = (tid < nb) ? blocksums[tid] : 0;
    sdata[tid] = v;
    __syncthreads();
    for (int off = 1; off < 256; off <<= 1) {
        int t = (tid >= off) ? sdata[tid - off] : 0;
        __syncthreads();
        sdata[tid] += t;
        __syncthreads();
    }
    if (tid < nb) blocksums[tid] = sdata[tid] - v;
}

__global__ void local_scan_kernel(int* __restrict__ counts,
                                  const int* __restrict__ blocksums,
                                  int* __restrict__ offsets, int n, int total) {
    __shared__ int sdata[SCAN_BLOCK];
    int tid = threadIdx.x;
    int i = blockIdx.x * SCAN_BLOCK + tid;
    int v = (i < n) ? counts[i] : 0;
    sdata[tid] = v;
    __syncthreads();
    for (int off = 1; off < SCAN_BLOCK; off <<= 1) {
        int t = (tid >= off) ? sdata[tid - off] : 0;
        __syncthreads();
        sdata[tid] += t;
        __syncthreads();
    }
    if (i < n) {
        int off = blocksums[blockIdx.x] + sdata[tid] - v;
        offsets[i] = off;
        counts[i] = off;   // becomes the scatter cursor
    }
    if (blockIdx.x == 0 && tid == 0) offsets[n] = total;
}

// ---------- gather (bf16 features, fp32 accumulate); x masked to 16-bit src --

__global__ void gather_bf16_kernel(const int* __restrict__ offsets,
                                   const int2* __restrict__ spack,
                                   const __hip_bfloat162* __restrict__ feat,
                                   const float2* __restrict__ bias2,
                                   float2* __restrict__ out2, int n_nodes) {
    int gtid = blockIdx.x * blockDim.x + threadIdx.x;
    int node = gtid >> 6;
    int lane = gtid & 63;
    if (node >= n_nodes) return;

    int beg = offsets[node];
    int end = offsets[node + 1];
    float2 acc0 = bias2[lane];
    float2 acc1 = make_float2(0.f, 0.f);

    int e = beg;
    for (; e + 8 <= end; e += 8) {
        int2 p[8];
        __hip_bfloat162 h[8];
#pragma unroll
        for (int j = 0; j < 8; j++) p[j] = spack[e + j];
#pragma unroll
        for (int j = 0; j < 8; j++)
            h[j] = feat[(size_t)(p[j].x & 0xFFFF) * 64 + lane];
#pragma unroll
        for (int j = 0; j < 8; j++) {
            float v = __int_as_float(p[j].y);
            float2 f = __bfloat1622float2(h[j]);
            if (j & 1) { acc1.x += v * f.x; acc1.y += v * f.y; }
            else       { acc0.x += v * f.x; acc0.y += v * f.y; }
        }
    }
    for (; e < end; e++) {
        int2 p = spack[e];
        float v = __int_as_float(p.y);
        float2 f = __bfloat1622float2(feat[(size_t)(p.x & 0xFFFF) * 64 + lane]);
        acc0.x += v * f.x; acc0.y += v * f.y;
    }
    acc0.x += acc1.x; acc0.y += acc1.y;
    out2[(size_t)node * 64 + lane] = acc0;
}

// ---------- fallback atomic path ----------

__global__ void init_bias_kernel(float4* __restrict__ out,
                                 const float4* __restrict__ bias, int n4) {
    int i = blockIdx.x * blockDim.x + threadIdx.x;
    if (i < n4) out[i] = bias[i & (D4 - 1)];
}

__global__ void spmm_edge_kernel(const int* __restrict__ src,
                                 const int* __restrict__ dst,
                                 const float* __restrict__ vals,
                                 const float4* __restrict__ feat,
                                 float* __restrict__ out, int n_edges) {
    int tid = blockIdx.x * blockDim.x + threadIdx.x;
    int e = tid >> 5;
    int lane = tid & 31;
    if (e >= n_edges) return;
    int s = src[e];
    int d = dst[e];
    float v = vals[e];
    float4 f = feat[(size_t)s * D4 + lane];
    float* o = out + (size_t)d * D_FEAT + lane * 4;
    atomicAdd(o + 0, v * f.x);
    atomicAdd(o + 1, v * f.y);
    atomicAdd(o + 2, v * f.z);
    atomicAdd(o + 3, v * f.w);
}

extern "C" void kernel_launch(void* const* d_in, const int* in_sizes, int n_in,
                              void* d_out, int out_size, void* d_ws, size_t ws_size,
                              hipStream_t stream) {
    const int* edge_index = (const int*)d_in[0];    // (2, E) int32
    const float* edge_vals = (const float*)d_in[1]; // (E,)
    const float* features  = (const float*)d_in[2]; // (N, 128)
    const float* bias      = (const float*)d_in[3]; // (128,)

    int E = in_sizes[1];
    int N = in_sizes[2] / D_FEAT;
    const int* src = edge_index;
    const int* dst = edge_index + E;
    float* out = (float*)d_out;

    int NBKT = (N + BKT_NODES - 1) >> BKT_SHIFT;
    int nseg = NBKT * NSLOT;
    int NBmid = (N + SCAN_BLOCK - 1) / SCAN_BLOCK;
    int n4 = N * D_FEAT / 4;

    size_t fb_bytes = (size_t)N * D_FEAT * 2;
    size_t sp_bytes = (size_t)E * 8;

    // NEW: fb16 | spackA | spackB | cur[nseg*16] | offsets[nseg+1] | nodeoff[N+1]
    size_t need_new = fb_bytes + 2 * sp_bytes +
                      ((size_t)nseg * CUR_PAD + (nseg + 1) + (N + 1)) * 4;
    // MID: fb16 | spack | offsets[N+1] | counts[N] | blocksums[NBmid]
    size_t need_mid = fb_bytes + sp_bytes +
                      ((size_t)(N + 1) + N + NBmid) * 4;

    bool base_ok = (N <= 65536) && (in_sizes[3] == D_FEAT) && (N >= 1) && (E >= 1);

    if (base_ok && ws_size >= need_new) {
        char* wp = (char*)d_ws;
        __hip_bfloat162* fb16 = (__hip_bfloat162*)wp;  wp += fb_bytes;
        int2* spackA = (int2*)wp;                      wp += sp_bytes;
        int2* spackB = (int2*)wp;                      wp += sp_bytes;
        int* cur     = (int*)wp;                       wp += (size_t)nseg * CUR_PAD * 4;
        int* offsets = (int*)wp;                       wp += (size_t)(nseg + 1) * 4;
        int* nodeoff = (int*)wp;

        hipMemsetAsync(cur, 0, (size_t)nseg * CUR_PAD * 4, stream);
        {
            int total = E + n4;
            int block = 256, grid = (total + block - 1) / block;
            hist_cvt_kernel<<<grid, block, 0, stream>>>(dst, cur, E,
                                                        (const float4*)features,
                                                        fb16, n4, 1);
        }
        scan_small_kernel<<<1, 1024, 0, stream>>>(cur, offsets, nseg);
        {
            int block = 256, grid = (E + block - 1) / block;
            partition_kernel<<<grid, block, 0, stream>>>(src, dst, edge_vals,
                                                         cur, spackA, E, 1);
        }
        bucket_sort_kernel<<<NBKT, 256, 0, stream>>>(offsets, spackA, spackB,
                                                     nodeoff, N, NBKT);
        {
            long long total = (long long)N * 64;
            int block = 256;
            int grid = (int)((total + block - 1) / block);
            gather_bf16_kernel<<<grid, block, 0, stream>>>(nodeoff, spackB, fb16,
                                                           (const float2*)bias,
                                                           (float2*)out, N);
        }
    } else if (base_ok && ws_size >= need_mid && NBmid <= 256) {
        char* wp = (char*)d_ws;
        __hip_bfloat162* fb16 = (__hip_bfloat162*)wp;  wp += fb_bytes;
        int2* spack  = (int2*)wp;                      wp += sp_bytes;
        int* offsets = (int*)wp;                       wp += (size_t)(N + 1) * 4;
        int* counts  = (int*)wp;                       wp += (size_t)N * 4;
        int* blocksums = (int*)wp;

        hipMemsetAsync(counts, 0, (size_t)N * 4, stream);
        {
            int total = E + n4;
            int block = 256, grid = (total + block - 1) / block;
            hist_cvt_kernel<<<grid, block, 0, stream>>>(dst, counts, E,
                                                        (const float4*)features,
                                                        fb16, n4, 0);
        }
        block_sums_kernel<<<NBmid, SCAN_BLOCK, 0, stream>>>(counts, blocksums, N);
        scan_sums_kernel<<<1, 256, 0, stream>>>(blocksums, NBmid);
        local_scan_kernel<<<NBmid, SCAN_BLOCK, 0, stream>>>(counts, blocksums,
                                                            offsets, N, E);
        {
            int block = 256, grid = (E + block - 1) / block;
            partition_kernel<<<grid, block, 0, stream>>>(src, dst, edge_vals,
                                                         counts, spack, E, 0);
        }
        {
            long long total = (long long)N * 64;
            int block = 256;
            int grid = (int)((total + block - 1) / block);
            gather_bf16_kernel<<<grid, block, 0, stream>>>(offsets, spack, fb16,
                                                           (const float2*)bias,
                                                           (float2*)out, N);
        }
    } else {
        int no4 = out_size / 4;
        {
            int block = 256, grid = (no4 + block - 1) / block;
            init_bias_kernel<<<grid, block, 0, stream>>>((float4*)out,
                                                         (const float4*)bias, no4);
        }
        {
            int block = 256;
            long long total = (long long)E * 32;
            int grid = (int)((total + block - 1) / block);
            spmm_edge_kernel<<<grid, block, 0, stream>>>(src, dst, edge_vals,
                                                         (const float4*)features,
                                                         out, E);
        }
    }
}